// Round 13
// baseline (5052.009 us; speedup 1.0000x reference)
//
#include <hip/hip_runtime.h>

#define TT 512
#define BB 64
#define NI 512
#define NH 1024
#define NG 4096

using bf16x8 = __attribute__((ext_vector_type(8))) __bf16;
using f32x4  = __attribute__((ext_vector_type(4))) float;

typedef __attribute__((address_space(3))) char       lds_char;
typedef const __attribute__((address_space(1))) char glb_char;

static __device__ __forceinline__ unsigned short f2bf(float f) {
  unsigned int u = __float_as_uint(f);
  u += 0x7fffu + ((u >> 16) & 1u);
  return (unsigned short)(u >> 16);
}

// ---------------- prep kernels (proven rounds 0-12) ----------------
__global__ void prep_layer(const float* __restrict__ Wih, const float* __restrict__ Whh,
                           const float* __restrict__ bih, const float* __restrict__ bhh,
                           unsigned short* __restrict__ Wx, unsigned short* __restrict__ Wh,
                           float* __restrict__ bias, int Kx) {
  long nx = (long)NG * Kx;
  long nh = (long)NG * NH;
  long total = nx + nh + NG;
  for (long i = (long)blockIdx.x * blockDim.x + threadIdx.x; i < total;
       i += (long)gridDim.x * blockDim.x) {
    if (i < nx) {
      int p = (int)(i / Kx); int k = (int)(i - (long)p * Kx);
      int orig = (p & 3) * NH + (p >> 2);
      Wx[i] = f2bf(Wih[(long)orig * Kx + k]);
    } else if (i < nx + nh) {
      long j = i - nx;
      int p = (int)(j / NH); int k = (int)(j - (long)p * NH);
      int orig = (p & 3) * NH + (p >> 2);
      Wh[j] = f2bf(Whh[(long)orig * NH + k]);
    } else {
      int p = (int)(i - nx - nh);
      int orig = (p & 3) * NH + (p >> 2);
      bias[p] = bih[orig] + bhh[orig];
    }
  }
}

__global__ void prep_emb(const int* __restrict__ tok, const int* __restrict__ lens,
                         const float* __restrict__ enc,
                         unsigned short* __restrict__ embf, unsigned short* __restrict__ embr) {
  int row = blockIdx.x;            // t*BB + b
  int t = row / BB, b = row - (row / BB) * BB;
  int L = lens[b];
  int tf = tok[b * TT + t];
  int ir = (t < L) ? (L - 1 - t) : t;
  int tr_ = tok[b * TT + ir];
  int i = threadIdx.x;             // 0..127 -> 4 floats each
  float4 vf = *(const float4*)(enc + (long)tf * NI + i * 4);
  float4 vr = *(const float4*)(enc + (long)tr_ * NI + i * 4);
  ushort4 of = make_ushort4(f2bf(vf.x), f2bf(vf.y), f2bf(vf.z), f2bf(vf.w));
  ushort4 orr = make_ushort4(f2bf(vr.x), f2bf(vr.y), f2bf(vr.z), f2bf(vr.w));
  *(ushort4*)(embf + (long)row * NI + i * 4) = of;
  *(ushort4*)(embr + (long)row * NI + i * 4) = orr;
}

// ---------------- main persistent kernel ----------------
// hist layout (BLOCKED, proven R7): hist[g][t][wl][row][c] bf16; tick stride
// 65536 elem, block stride 1024 (2KB, written as 16 full 128B lines).
// slots (R7-proven PADDED): u32 at slots[wg*8] (32B per wg).
struct KP {
  const int* lens;
  const unsigned short* emb[2];    // [dir] (T*B, NI) bf16 row-major
  const unsigned short* Wx[4];     // [g] (NG, Kx) bf16, permuted rows
  const unsigned short* Wh[4];     // [g] (NG, NH) bf16, permuted rows
  const float* bias[4];            // [g] (NG) f32, permuted rows
  unsigned short* hist[4];         // [g] blocked write-once h history
  unsigned int* slots;             // 256 wg slots, 32B padded (slots[wg*8])
  float* out;                      // (T, B, 2048) f32
};

// combined subset poll (R11-proven): lanes 0-7 own-group producers (blocks
// v*8..v*8+7, target t, only if t>0); lanes 8-15 prev-group (target t+1,
// only if layer==1). Other lanes idle-true.
static __device__ __forceinline__ void poll_comb(const unsigned int* slots, int g,
                                                 int v, int layer, int t) {
  const int lane = threadIdx.x & 63;
  const bool nown = (t > 0) && (lane < 8);
  const bool nprev = layer && (lane >= 8) && (lane < 16);
  const unsigned int* p = slots;   // harmless default (value >= 0 always)
  unsigned tgt = 0u;
  if (nown)  { p = slots + (size_t)(g * 64 + v * 8 + lane) * 8;            tgt = (unsigned)t; }
  if (nprev) { p = slots + (size_t)((g - 1) * 64 + v * 8 + (lane - 8)) * 8; tgt = (unsigned)(t + 1); }
  for (;;) {
    unsigned val = __hip_atomic_load(p, __ATOMIC_RELAXED, __HIP_MEMORY_SCOPE_AGENT);
    if (__all((int)(val >= tgt))) break;
    __builtin_amdgcn_s_sleep(1);
  }
  asm volatile("" ::: "memory");
}

// 256 wgs x 512 thr. group g = wg>>6: 0=f0 1=f1 2=r0 3=r1 (dir=g>>1, layer=g&1).
// wg owns 64 permuted gate rows (16 h-cols). ALL 8 waves: K-eighth of h
// (K=128, LDS-staged via global_load_lds) + K-eighth of x.
// red (128KB) is time-shared: wave v's 16KB stage slice == its red slice.
// R13 = R11 + layer-0 emb prefetch one tick ahead (sole change).
__global__ void __launch_bounds__(512, 2) lstm_main(KP P) {
  __shared__ f32x4 red[8 * 16 * 64];          // 128 KB stage/partial (aliased)
  __shared__ unsigned short hrep[64][16];     // 2 KB   h repack == dest block image
  __shared__ float hrep2[64][17];             // 4.25KB out repack (f32, padded)
  const int tid = threadIdx.x, lane = tid & 63, wave = tid >> 6;
  const int v = wave;                          // K-eighth index
  const int wg = blockIdx.x, g = wg >> 6, wl = wg & 63;
  const int dir = g >> 1, layer = g & 1;
  const int ln = lane & 15, kg = lane >> 4;

  // ---- weights: h K-eighth (16 frags) + x K-eighth (8 or 16 frags) ----
  bf16x8 wh[16], wx[16];
  const int row0 = wl * 64;
  {
    const unsigned short* Wh = P.Wh[g];
#pragma unroll
    for (int mt = 0; mt < 4; ++mt) {
      const unsigned short* p = Wh + (long)(row0 + mt * 16 + ln) * NH + v * 128 + kg * 8;
#pragma unroll
      for (int kk = 0; kk < 4; ++kk) wh[mt * 4 + kk] = *(const bf16x8*)(p + kk * 32);
    }
    const unsigned short* Wxp = P.Wx[g];
    if (layer) {
#pragma unroll
      for (int mt = 0; mt < 4; ++mt) {
        const unsigned short* p = Wxp + (long)(row0 + mt * 16 + ln) * NH + v * 128 + kg * 8;
#pragma unroll
        for (int kk = 0; kk < 4; ++kk) wx[mt * 4 + kk] = *(const bf16x8*)(p + kk * 32);
      }
    } else {
#pragma unroll
      for (int mt = 0; mt < 4; ++mt) {
        const unsigned short* p = Wxp + (long)(row0 + mt * 16 + ln) * NI + v * 64 + kg * 8;
#pragma unroll
        for (int kk = 0; kk < 2; ++kk) wx[mt * 2 + kk] = *(const bf16x8*)(p + kk * 32);
      }
#pragma unroll
      for (int i = 8; i < 16; ++i) wx[i] = (bf16x8)0;
    }
  }
#pragma unroll
  for (int i = 0; i < 16; ++i) {
    asm volatile("" : "+v"(reinterpret_cast<f32x4&>(wh[i])));
    asm volatile("" : "+v"(reinterpret_cast<f32x4&>(wx[i])));
  }

  unsigned short* hist = P.hist[g];
  const unsigned short* xprev = layer ? (const unsigned short*)P.hist[g - 1] : nullptr;
  const unsigned short* xemb = P.emb[dir];

  // epilogue constants (R11-identical): thread -> units i0=wave*2, i0+1
  const int i0 = wave * 2;
  const int coll = (i0 >> 2) * 4 + kg;        // col within wg's 16
  const int b0 = (i0 & 3) * 16 + ln;
  const int b1 = ((i0 + 1) & 3) * 16 + ln;
  const f32x4 bias_v = *(const f32x4*)(P.bias[g] + (wl * 16 + coll) * 4);
  const int L0 = P.lens[b0], L1 = P.lens[b1];
  float c0 = 0.f, c1 = 0.f;

  // out-store constants (R11-identical)
  const int sr = wave * 8 + (lane >> 3);
  const int sc = lane & 7;

  // LDS stage slice for this wave (aliases red; byte base v*16384)
  lds_char* lslice = (lds_char*)((char*)red + v * 16384);

  // layer-0: emb B-frags for tick 0, prefetched (static data, off crit path)
  bf16x8 pre[8];
  if (!layer) {
    const unsigned short* pb = xemb + (size_t)ln * NI + v * 64 + kg * 8;
#pragma unroll
    for (int kk = 0; kk < 2; ++kk)
#pragma unroll
      for (int nt = 0; nt < 4; ++nt)
        pre[kk * 4 + nt] = *(const bf16x8*)(pb + kk * 32 + (size_t)nt * 16 * NI);
  }

  for (int t = 0; t < TT; ++t) {
    f32x4 acc[16];
#pragma unroll
    for (int i = 0; i < 16; ++i) { f32x4 z = {0.f, 0.f, 0.f, 0.f}; acc[i] = z; }

    if (t > 0 || layer) poll_comb(P.slots, g, v, layer, t);

    // issue h stage: 16 x global_load_lds of 1KB (blocks v*8..v*8+7 of t-1)
    if (t > 0) {
      const char* gsrc = (const char*)(hist + (size_t)(t - 1) * 65536 + (size_t)v * 8192);
#pragma unroll
      for (int c = 0; c < 16; ++c) {
        __builtin_amdgcn_global_load_lds(
            (glb_char*)(gsrc + c * 1024 + lane * 16),
            (lds_char*)(lslice + c * 1024), 16, 0, 0);
      }
    }

    // x-gemm while the stage flies
    if (layer) {
      const unsigned short* pb = xprev + (size_t)t * 65536 +
          (size_t)(v * 8 + (kg >> 1)) * 1024 + ln * 16 + (kg & 1) * 8;
      bf16x8 bx[4][4];
#pragma unroll
      for (int kk = 0; kk < 4; ++kk)
#pragma unroll
        for (int nt = 0; nt < 4; ++nt)
          bx[kk][nt] = *(const bf16x8*)(pb + kk * 2048 + nt * 256);
#pragma unroll
      for (int kk = 0; kk < 4; ++kk)
#pragma unroll
        for (int mt = 0; mt < 4; ++mt)
#pragma unroll
          for (int nt = 0; nt < 4; ++nt)
            acc[mt * 4 + nt] = __builtin_amdgcn_mfma_f32_16x16x32_bf16(
                wx[mt * 4 + kk], bx[kk][nt], acc[mt * 4 + nt], 0, 0, 0);
    } else {
#pragma unroll
      for (int kk = 0; kk < 2; ++kk)
#pragma unroll
        for (int mt = 0; mt < 4; ++mt)
#pragma unroll
          for (int nt = 0; nt < 4; ++nt)
            acc[mt * 4 + nt] = __builtin_amdgcn_mfma_f32_16x16x32_bf16(
                wx[mt * 2 + kk], pre[kk * 4 + nt], acc[mt * 4 + nt], 0, 0, 0);
    }

    // h-gemm from LDS (staged); double-buffered ds_reads (R11-proven)
    if (t > 0) {
      asm volatile("s_waitcnt vmcnt(0)" ::: "memory");  // stage landed in LDS
      __builtin_amdgcn_sched_barrier(0);
      const char* ls = (const char*)red + v * 16384 +
                       (kg >> 1) * 2048 + ln * 32 + (kg & 1) * 16;
      bf16x8 bh[2][4];
#pragma unroll
      for (int nt = 0; nt < 4; ++nt)
        bh[0][nt] = *(const bf16x8*)(ls + nt * 512);
#pragma unroll
      for (int kk = 0; kk < 4; ++kk) {
        if (kk < 3) {
#pragma unroll
          for (int nt = 0; nt < 4; ++nt)
            bh[(kk + 1) & 1][nt] = *(const bf16x8*)(ls + (kk + 1) * 4096 + nt * 512);
        }
#pragma unroll
        for (int mt = 0; mt < 4; ++mt)
#pragma unroll
          for (int nt = 0; nt < 4; ++nt)
            acc[mt * 4 + nt] = __builtin_amdgcn_mfma_f32_16x16x32_bf16(
                wh[mt * 4 + kk], bh[kk & 1][nt], acc[mt * 4 + nt], 0, 0, 0);
      }
      asm volatile("s_waitcnt lgkmcnt(0)" ::: "memory"); // reads done (WAR)
      __builtin_amdgcn_sched_barrier(0);
    }

#pragma unroll
    for (int i = 0; i < 16; ++i) red[(wave * 16 + i) * 64 + lane] = acc[i];
    __syncthreads();                                   // #1: partials ready

    // epilogue (R11-identical: lane-contiguous red reads, conflict-free)
#pragma unroll
    for (int u = 0; u < 2; ++u) {
      const int i = i0 + u;
      f32x4 gs = bias_v;
#pragma unroll
      for (int w2 = 0; w2 < 8; ++w2) gs += red[(w2 * 16 + i) * 64 + lane];
      float iv = 1.f / (1.f + __expf(-gs[0]));
      float fv = 1.f / (1.f + __expf(-gs[1]));
      float gv = 1.f - 2.f / (1.f + __expf(2.f * gs[2]));
      float og = 1.f / (1.f + __expf(-gs[3]));
      float cp = u ? c1 : c0;
      float cn = fv * cp + iv * gv;
      if (u) c1 = cn; else c0 = cn;
      float tc = 1.f - 2.f / (1.f + __expf(2.f * cn));
      float hn = og * tc;
      const int Lx = u ? L1 : L0;
      const int bx = u ? b1 : b0;
      float outv = (t < Lx) ? hn : 0.f;   // masked rows feed only masked rows
      hrep[bx][coll] = f2bf(outv);
      if (layer) hrep2[bx][coll] = outv;
    }
    __syncthreads();                                   // #2: hrep ready

    // h store + drain + barrier + release (R7/R11-identical)
    {
      unsigned vv = ((const unsigned*)hrep)[tid];
      __hip_atomic_store(
          (unsigned*)(hist + (size_t)t * 65536 + (size_t)wl * 1024) + tid,
          vv, __ATOMIC_RELAXED, __HIP_MEMORY_SCOPE_AGENT);
    }
    asm volatile("s_waitcnt vmcnt(0)" ::: "memory");
    __syncthreads();                                   // #3: all waves drained
    if (tid == 0)
      __hip_atomic_store(P.slots + (size_t)wg * 8, (unsigned)(t + 1),
                         __ATOMIC_RELAXED, __HIP_MEMORY_SCOPE_AGENT);
    if (layer) {
#pragma unroll
      for (int u = 0; u < 2; ++u) {
        float vv = hrep2[sr][sc + u * 8];
        __builtin_nontemporal_store(
            vv, &P.out[(long)(t * BB + sr) * 2048 + dir * NH + wl * 16 + sc + u * 8]);
      }
    } else if (t + 1 < TT) {   // prefetch emb B-frags for tick t+1 (static,
                               // L2-cached; compiler inserts the waitcnt
                               // before first use next tick)
      const unsigned short* pb = xemb + ((size_t)(t + 1) * BB + ln) * NI + v * 64 + kg * 8;
#pragma unroll
      for (int kk = 0; kk < 2; ++kk)
#pragma unroll
        for (int nt = 0; nt < 4; ++nt)
          pre[kk * 4 + nt] = *(const bf16x8*)(pb + kk * 32 + (size_t)nt * 16 * NI);
    }
  }
}

extern "C" void kernel_launch(void* const* d_in, const int* in_sizes, int n_in,
                              void* d_out, int out_size, void* d_ws, size_t ws_size,
                              hipStream_t stream) {
  (void)in_sizes; (void)n_in; (void)out_size; (void)ws_size;
  const int* input = (const int*)d_in[0];
  const int* lens  = (const int*)d_in[1];
  const float* enc = (const float*)d_in[2];
  // g = dir*2+layer: 0=f0(3..6) 1=f1(7..10) 2=r0(11..14) 3=r1(15..18)
  const float* Wih[4] = {(const float*)d_in[3],  (const float*)d_in[7],
                         (const float*)d_in[11], (const float*)d_in[15]};
  const float* Whh[4] = {(const float*)d_in[4],  (const float*)d_in[8],
                         (const float*)d_in[12], (const float*)d_in[16]};
  const float* bih[4] = {(const float*)d_in[5],  (const float*)d_in[9],
                         (const float*)d_in[13], (const float*)d_in[17]};
  const float* bhh[4] = {(const float*)d_in[6],  (const float*)d_in[10],
                         (const float*)d_in[14], (const float*)d_in[18]};

  char* ws = (char*)d_ws;
  size_t off = 0;
  auto carve = [&](size_t bytes) -> char* {
    char* p = ws + off;
    off += (bytes + 255) & ~(size_t)255;
    return p;
  };
  unsigned short* emb[2];
  emb[0] = (unsigned short*)carve((size_t)TT * BB * NI * 2);
  emb[1] = (unsigned short*)carve((size_t)TT * BB * NI * 2);
  unsigned short* hist[4];
  for (int g = 0; g < 4; ++g)
    hist[g] = (unsigned short*)carve((size_t)TT * BB * NH * 2);
  unsigned short* Wx[4]; unsigned short* Wh[4]; float* bias[4];
  for (int li = 0; li < 4; ++li) {
    int Kx = (li & 1) ? NH : NI;
    Wx[li]   = (unsigned short*)carve((size_t)NG * Kx * 2);
    Wh[li]   = (unsigned short*)carve((size_t)NG * NH * 2);
    bias[li] = (float*)carve((size_t)NG * 4);
  }
  unsigned int* slots = (unsigned int*)carve(256 * 32);

  hipMemsetAsync(slots, 0, 256 * 32, stream);
  for (int li = 0; li < 4; ++li) {
    int Kx = (li & 1) ? NH : NI;
    prep_layer<<<2048, 256, 0, stream>>>(Wih[li], Whh[li], bih[li], bhh[li],
                                         Wx[li], Wh[li], bias[li], Kx);
  }
  prep_emb<<<TT * BB, 128, 0, stream>>>(input, lens, enc, emb[0], emb[1]);

  KP p;
  p.lens = lens;
  p.emb[0] = emb[0]; p.emb[1] = emb[1];
  for (int li = 0; li < 4; ++li) {
    p.Wx[li] = Wx[li]; p.Wh[li] = Wh[li]; p.bias[li] = bias[li]; p.hist[li] = hist[li];
  }
  p.slots = slots;
  p.out = (float*)d_out;

  void* args[] = {&p};
  hipLaunchCooperativeKernel(lstm_main, dim3(256), dim3(512), args, 0, stream);
}

// Round 14
// 3848.671 us; speedup vs baseline: 1.3127x; 1.3127x over previous
//
#include <hip/hip_runtime.h>

#define TT 512
#define BB 64
#define NI 512
#define NH 1024
#define NG 4096

using bf16x8 = __attribute__((ext_vector_type(8))) __bf16;
using f32x4  = __attribute__((ext_vector_type(4))) float;

typedef __attribute__((address_space(3))) char       lds_char;
typedef const __attribute__((address_space(1))) char glb_char;

static __device__ __forceinline__ unsigned short f2bf(float f) {
  unsigned int u = __float_as_uint(f);
  u += 0x7fffu + ((u >> 16) & 1u);
  return (unsigned short)(u >> 16);
}

// ---------------- prep kernels (proven rounds 0-13) ----------------
__global__ void prep_layer(const float* __restrict__ Wih, const float* __restrict__ Whh,
                           const float* __restrict__ bih, const float* __restrict__ bhh,
                           unsigned short* __restrict__ Wx, unsigned short* __restrict__ Wh,
                           float* __restrict__ bias, int Kx) {
  long nx = (long)NG * Kx;
  long nh = (long)NG * NH;
  long total = nx + nh + NG;
  for (long i = (long)blockIdx.x * blockDim.x + threadIdx.x; i < total;
       i += (long)gridDim.x * blockDim.x) {
    if (i < nx) {
      int p = (int)(i / Kx); int k = (int)(i - (long)p * Kx);
      int orig = (p & 3) * NH + (p >> 2);
      Wx[i] = f2bf(Wih[(long)orig * Kx + k]);
    } else if (i < nx + nh) {
      long j = i - nx;
      int p = (int)(j / NH); int k = (int)(j - (long)p * NH);
      int orig = (p & 3) * NH + (p >> 2);
      Wh[j] = f2bf(Whh[(long)orig * NH + k]);
    } else {
      int p = (int)(i - nx - nh);
      int orig = (p & 3) * NH + (p >> 2);
      bias[p] = bih[orig] + bhh[orig];
    }
  }
}

__global__ void prep_emb(const int* __restrict__ tok, const int* __restrict__ lens,
                         const float* __restrict__ enc,
                         unsigned short* __restrict__ embf, unsigned short* __restrict__ embr) {
  int row = blockIdx.x;            // t*BB + b
  int t = row / BB, b = row - (row / BB) * BB;
  int L = lens[b];
  int tf = tok[b * TT + t];
  int ir = (t < L) ? (L - 1 - t) : t;
  int tr_ = tok[b * TT + ir];
  int i = threadIdx.x;             // 0..127 -> 4 floats each
  float4 vf = *(const float4*)(enc + (long)tf * NI + i * 4);
  float4 vr = *(const float4*)(enc + (long)tr_ * NI + i * 4);
  ushort4 of = make_ushort4(f2bf(vf.x), f2bf(vf.y), f2bf(vf.z), f2bf(vf.w));
  ushort4 orr = make_ushort4(f2bf(vr.x), f2bf(vr.y), f2bf(vr.z), f2bf(vr.w));
  *(ushort4*)(embf + (long)row * NI + i * 4) = of;
  *(ushort4*)(embr + (long)row * NI + i * 4) = orr;
}

// ---------------- main persistent kernel ----------------
// hist layout (BLOCKED, proven R7): hist[g][t][wl][row][c] bf16; tick stride
// 65536 elem, block stride 1024 (2KB, written as 16 full 128B lines).
// slots (R7-proven PADDED): u32 at slots[lid*8] (32B per logical wg).
struct KP {
  const int* lens;
  const unsigned short* emb[2];    // [dir] (T*B, NI) bf16 row-major
  const unsigned short* Wx[4];     // [g] (NG, Kx) bf16, permuted rows
  const unsigned short* Wh[4];     // [g] (NG, NH) bf16, permuted rows
  const float* bias[4];            // [g] (NG) f32, permuted rows
  unsigned short* hist[4];         // [g] blocked write-once h history
  unsigned int* slots;             // 256 logical slots, 32B padded
  float* out;                      // (T, B, 2048) f32
};

// combined subset poll (R11-proven): lanes 0-7 own-group producers (blocks
// v*8..v*8+7, target t, only if t>0); lanes 8-15 prev-group (target t+1,
// only if layer==1). Other lanes idle-true. Indexed by LOGICAL wg id.
static __device__ __forceinline__ void poll_comb(const unsigned int* slots, int g,
                                                 int v, int layer, int t) {
  const int lane = threadIdx.x & 63;
  const bool nown = (t > 0) && (lane < 8);
  const bool nprev = layer && (lane >= 8) && (lane < 16);
  const unsigned int* p = slots;   // harmless default (value >= 0 always)
  unsigned tgt = 0u;
  if (nown)  { p = slots + (size_t)(g * 64 + v * 8 + lane) * 8;            tgt = (unsigned)t; }
  if (nprev) { p = slots + (size_t)((g - 1) * 64 + v * 8 + (lane - 8)) * 8; tgt = (unsigned)(t + 1); }
  for (;;) {
    unsigned val = __hip_atomic_load(p, __ATOMIC_RELAXED, __HIP_MEMORY_SCOPE_AGENT);
    if (__all((int)(val >= tgt))) break;
    __builtin_amdgcn_s_sleep(1);
  }
  asm volatile("" ::: "memory");
}

// 256 wgs x 512 thr. XCD-aware mapping (R14, sole change vs R11):
// xcd = blockIdx&7, group g = xcd>>1, wl = (blockIdx>>3)*2 + (xcd&1).
// Each group lives on its own XCD pair -> 32 same-group wgs share each
// fetched h-line in that XCD's L2 (was 8), 4x fewer L3->L2 fetches.
// wg owns 64 permuted gate rows (16 h-cols). ALL 8 waves: K-eighth of h
// (K=128, LDS-staged via global_load_lds) + K-eighth of x.
// red (128KB) is time-shared: wave v's 16KB stage slice == its red slice.
// Store/sync protocol = EXACT R7/R11-proven skeleton.
__global__ void __launch_bounds__(512, 2) lstm_main(KP P) {
  __shared__ f32x4 red[8 * 16 * 64];          // 128 KB stage/partial (aliased)
  __shared__ unsigned short hrep[64][16];     // 2 KB   h repack == dest block image
  __shared__ float hrep2[64][17];             // 4.25KB out repack (f32, padded)
  const int tid = threadIdx.x, lane = tid & 63, wave = tid >> 6;
  const int v = wave;                          // K-eighth index
  const int xcd = blockIdx.x & 7;
  const int g = xcd >> 1;                      // group on XCD pair {2g, 2g+1}
  const int wl = ((blockIdx.x >> 3) << 1) + (xcd & 1);
  const int lid = g * 64 + wl;                 // logical wg id (slots index)
  const int dir = g >> 1, layer = g & 1;
  const int ln = lane & 15, kg = lane >> 4;

  // ---- weights: h K-eighth (16 frags) + x K-eighth (8 or 16 frags) ----
  bf16x8 wh[16], wx[16];
  const int row0 = wl * 64;
  {
    const unsigned short* Wh = P.Wh[g];
#pragma unroll
    for (int mt = 0; mt < 4; ++mt) {
      const unsigned short* p = Wh + (long)(row0 + mt * 16 + ln) * NH + v * 128 + kg * 8;
#pragma unroll
      for (int kk = 0; kk < 4; ++kk) wh[mt * 4 + kk] = *(const bf16x8*)(p + kk * 32);
    }
    const unsigned short* Wxp = P.Wx[g];
    if (layer) {
#pragma unroll
      for (int mt = 0; mt < 4; ++mt) {
        const unsigned short* p = Wxp + (long)(row0 + mt * 16 + ln) * NH + v * 128 + kg * 8;
#pragma unroll
        for (int kk = 0; kk < 4; ++kk) wx[mt * 4 + kk] = *(const bf16x8*)(p + kk * 32);
      }
    } else {
#pragma unroll
      for (int mt = 0; mt < 4; ++mt) {
        const unsigned short* p = Wxp + (long)(row0 + mt * 16 + ln) * NI + v * 64 + kg * 8;
#pragma unroll
        for (int kk = 0; kk < 2; ++kk) wx[mt * 2 + kk] = *(const bf16x8*)(p + kk * 32);
      }
#pragma unroll
      for (int i = 8; i < 16; ++i) wx[i] = (bf16x8)0;
    }
  }
#pragma unroll
  for (int i = 0; i < 16; ++i) {
    asm volatile("" : "+v"(reinterpret_cast<f32x4&>(wh[i])));
    asm volatile("" : "+v"(reinterpret_cast<f32x4&>(wx[i])));
  }

  unsigned short* hist = P.hist[g];
  const unsigned short* xprev = layer ? (const unsigned short*)P.hist[g - 1] : nullptr;
  const unsigned short* xemb = P.emb[dir];

  // epilogue constants (R11-identical): thread -> units i0=wave*2, i0+1
  const int i0 = wave * 2;
  const int coll = (i0 >> 2) * 4 + kg;        // col within wg's 16
  const int b0 = (i0 & 3) * 16 + ln;
  const int b1 = ((i0 + 1) & 3) * 16 + ln;
  const f32x4 bias_v = *(const f32x4*)(P.bias[g] + (wl * 16 + coll) * 4);
  const int L0 = P.lens[b0], L1 = P.lens[b1];
  float c0 = 0.f, c1 = 0.f;

  // out-store constants (R11-identical)
  const int sr = wave * 8 + (lane >> 3);
  const int sc = lane & 7;

  // LDS stage slice for this wave (aliases red; byte base v*16384)
  lds_char* lslice = (lds_char*)((char*)red + v * 16384);

  for (int t = 0; t < TT; ++t) {
    f32x4 acc[16];
#pragma unroll
    for (int i = 0; i < 16; ++i) { f32x4 z = {0.f, 0.f, 0.f, 0.f}; acc[i] = z; }

    if (t > 0 || layer) poll_comb(P.slots, g, v, layer, t);

    // issue h stage: 16 x global_load_lds of 1KB (blocks v*8..v*8+7 of t-1)
    if (t > 0) {
      const char* gsrc = (const char*)(hist + (size_t)(t - 1) * 65536 + (size_t)v * 8192);
#pragma unroll
      for (int c = 0; c < 16; ++c) {
        __builtin_amdgcn_global_load_lds(
            (glb_char*)(gsrc + c * 1024 + lane * 16),
            (lds_char*)(lslice + c * 1024), 16, 0, 0);
      }
    }

    // x-gemm while the stage flies (R11-identical: loads at point of use)
    if (layer) {
      const unsigned short* pb = xprev + (size_t)t * 65536 +
          (size_t)(v * 8 + (kg >> 1)) * 1024 + ln * 16 + (kg & 1) * 8;
      bf16x8 bx[4][4];
#pragma unroll
      for (int kk = 0; kk < 4; ++kk)
#pragma unroll
        for (int nt = 0; nt < 4; ++nt)
          bx[kk][nt] = *(const bf16x8*)(pb + kk * 2048 + nt * 256);
#pragma unroll
      for (int kk = 0; kk < 4; ++kk)
#pragma unroll
        for (int mt = 0; mt < 4; ++mt)
#pragma unroll
          for (int nt = 0; nt < 4; ++nt)
            acc[mt * 4 + nt] = __builtin_amdgcn_mfma_f32_16x16x32_bf16(
                wx[mt * 4 + kk], bx[kk][nt], acc[mt * 4 + nt], 0, 0, 0);
    } else {
      const unsigned short* pb = xemb + ((size_t)t * BB + ln) * NI + v * 64 + kg * 8;
      bf16x8 bx[2][4];
#pragma unroll
      for (int kk = 0; kk < 2; ++kk)
#pragma unroll
        for (int nt = 0; nt < 4; ++nt)
          bx[kk][nt] = *(const bf16x8*)(pb + kk * 32 + (size_t)nt * 16 * NI);
#pragma unroll
      for (int kk = 0; kk < 2; ++kk)
#pragma unroll
        for (int mt = 0; mt < 4; ++mt)
#pragma unroll
          for (int nt = 0; nt < 4; ++nt)
            acc[mt * 4 + nt] = __builtin_amdgcn_mfma_f32_16x16x32_bf16(
                wx[mt * 2 + kk], bx[kk][nt], acc[mt * 4 + nt], 0, 0, 0);
    }

    // h-gemm from LDS (staged); double-buffered ds_reads (R11-proven)
    if (t > 0) {
      asm volatile("s_waitcnt vmcnt(0)" ::: "memory");  // stage landed in LDS
      __builtin_amdgcn_sched_barrier(0);
      const char* ls = (const char*)red + v * 16384 +
                       (kg >> 1) * 2048 + ln * 32 + (kg & 1) * 16;
      bf16x8 bh[2][4];
#pragma unroll
      for (int nt = 0; nt < 4; ++nt)
        bh[0][nt] = *(const bf16x8*)(ls + nt * 512);
#pragma unroll
      for (int kk = 0; kk < 4; ++kk) {
        if (kk < 3) {
#pragma unroll
          for (int nt = 0; nt < 4; ++nt)
            bh[(kk + 1) & 1][nt] = *(const bf16x8*)(ls + (kk + 1) * 4096 + nt * 512);
        }
#pragma unroll
        for (int mt = 0; mt < 4; ++mt)
#pragma unroll
          for (int nt = 0; nt < 4; ++nt)
            acc[mt * 4 + nt] = __builtin_amdgcn_mfma_f32_16x16x32_bf16(
                wh[mt * 4 + kk], bh[kk & 1][nt], acc[mt * 4 + nt], 0, 0, 0);
      }
      asm volatile("s_waitcnt lgkmcnt(0)" ::: "memory"); // reads done (WAR)
      __builtin_amdgcn_sched_barrier(0);
    }

#pragma unroll
    for (int i = 0; i < 16; ++i) red[(wave * 16 + i) * 64 + lane] = acc[i];
    __syncthreads();                                   // #1: partials ready

    // epilogue (R11-identical: lane-contiguous red reads, conflict-free)
#pragma unroll
    for (int u = 0; u < 2; ++u) {
      const int i = i0 + u;
      f32x4 gs = bias_v;
#pragma unroll
      for (int w2 = 0; w2 < 8; ++w2) gs += red[(w2 * 16 + i) * 64 + lane];
      float iv = 1.f / (1.f + __expf(-gs[0]));
      float fv = 1.f / (1.f + __expf(-gs[1]));
      float gv = 1.f - 2.f / (1.f + __expf(2.f * gs[2]));
      float og = 1.f / (1.f + __expf(-gs[3]));
      float cp = u ? c1 : c0;
      float cn = fv * cp + iv * gv;
      if (u) c1 = cn; else c0 = cn;
      float tc = 1.f - 2.f / (1.f + __expf(2.f * cn));
      float hn = og * tc;
      const int Lx = u ? L1 : L0;
      const int bx = u ? b1 : b0;
      float outv = (t < Lx) ? hn : 0.f;   // masked rows feed only masked rows
      hrep[bx][coll] = f2bf(outv);
      if (layer) hrep2[bx][coll] = outv;
    }
    __syncthreads();                                   // #2: hrep ready

    // h store + drain + barrier + release (R7/R11-identical)
    {
      unsigned vv = ((const unsigned*)hrep)[tid];
      __hip_atomic_store(
          (unsigned*)(hist + (size_t)t * 65536 + (size_t)wl * 1024) + tid,
          vv, __ATOMIC_RELAXED, __HIP_MEMORY_SCOPE_AGENT);
    }
    asm volatile("s_waitcnt vmcnt(0)" ::: "memory");
    __syncthreads();                                   // #3: all waves drained
    if (tid == 0)
      __hip_atomic_store(P.slots + (size_t)lid * 8, (unsigned)(t + 1),
                         __ATOMIC_RELAXED, __HIP_MEMORY_SCOPE_AGENT);
    if (layer) {
#pragma unroll
      for (int u = 0; u < 2; ++u) {
        float vv = hrep2[sr][sc + u * 8];
        __builtin_nontemporal_store(
            vv, &P.out[(long)(t * BB + sr) * 2048 + dir * NH + wl * 16 + sc + u * 8]);
      }
    }
  }
}

extern "C" void kernel_launch(void* const* d_in, const int* in_sizes, int n_in,
                              void* d_out, int out_size, void* d_ws, size_t ws_size,
                              hipStream_t stream) {
  (void)in_sizes; (void)n_in; (void)out_size; (void)ws_size;
  const int* input = (const int*)d_in[0];
  const int* lens  = (const int*)d_in[1];
  const float* enc = (const float*)d_in[2];
  // g = dir*2+layer: 0=f0(3..6) 1=f1(7..10) 2=r0(11..14) 3=r1(15..18)
  const float* Wih[4] = {(const float*)d_in[3],  (const float*)d_in[7],
                         (const float*)d_in[11], (const float*)d_in[15]};
  const float* Whh[4] = {(const float*)d_in[4],  (const float*)d_in[8],
                         (const float*)d_in[12], (const float*)d_in[16]};
  const float* bih[4] = {(const float*)d_in[5],  (const float*)d_in[9],
                         (const float*)d_in[13], (const float*)d_in[17]};
  const float* bhh[4] = {(const float*)d_in[6],  (const float*)d_in[10],
                         (const float*)d_in[14], (const float*)d_in[18]};

  char* ws = (char*)d_ws;
  size_t off = 0;
  auto carve = [&](size_t bytes) -> char* {
    char* p = ws + off;
    off += (bytes + 255) & ~(size_t)255;
    return p;
  };
  unsigned short* emb[2];
  emb[0] = (unsigned short*)carve((size_t)TT * BB * NI * 2);
  emb[1] = (unsigned short*)carve((size_t)TT * BB * NI * 2);
  unsigned short* hist[4];
  for (int g = 0; g < 4; ++g)
    hist[g] = (unsigned short*)carve((size_t)TT * BB * NH * 2);
  unsigned short* Wx[4]; unsigned short* Wh[4]; float* bias[4];
  for (int li = 0; li < 4; ++li) {
    int Kx = (li & 1) ? NH : NI;
    Wx[li]   = (unsigned short*)carve((size_t)NG * Kx * 2);
    Wh[li]   = (unsigned short*)carve((size_t)NG * NH * 2);
    bias[li] = (float*)carve((size_t)NG * 4);
  }
  unsigned int* slots = (unsigned int*)carve(256 * 32);

  hipMemsetAsync(slots, 0, 256 * 32, stream);
  for (int li = 0; li < 4; ++li) {
    int Kx = (li & 1) ? NH : NI;
    prep_layer<<<2048, 256, 0, stream>>>(Wih[li], Whh[li], bih[li], bhh[li],
                                         Wx[li], Wh[li], bias[li], Kx);
  }
  prep_emb<<<TT * BB, 128, 0, stream>>>(input, lens, enc, emb[0], emb[1]);

  KP p;
  p.lens = lens;
  p.emb[0] = emb[0]; p.emb[1] = emb[1];
  for (int li = 0; li < 4; ++li) {
    p.Wx[li] = Wx[li]; p.Wh[li] = Wh[li]; p.bias[li] = bias[li]; p.hist[li] = hist[li];
  }
  p.slots = slots;
  p.out = (float*)d_out;

  void* args[] = {&p};
  hipLaunchCooperativeKernel(lstm_main, dim3(256), dim3(512), args, 0, stream);
}